// Round 1
// baseline (276.998 us; speedup 1.0000x reference)
//
#include <hip/hip_runtime.h>

// Shapes
#define NB   256      // batch
#define E0   300      // embedding
#define EP   304      // padded embedding (mult of 8 -> no chunk straddle)
#define F_   512      // features
#define KP   1536     // padded K (5*304=1520 -> 48*32)
#define NKT  48       // K-steps of 32
#define LQ_  64
#define LA_  256

typedef __attribute__((ext_vector_type(4))) float f32x4;
typedef __attribute__((ext_vector_type(8))) short short8;

#define XQ_ELEMS (NB * (LQ_ + 4) * EP)   // 5,292,032
#define XA_ELEMS (NB * (LA_ + 4) * EP)   // 20,234,240
#define WT_ELEMS (F_ * KP)               // 786,432
#define OUTQ_ELEMS ((size_t)NB * F_ * LQ_)

__device__ __forceinline__ unsigned short f2bf(float x) {
    unsigned int u = __float_as_uint(x);
    u = u + 0x7fffu + ((u >> 16) & 1u);   // RNE
    return (unsigned short)(u >> 16);
}

// Build zero-padded bf16 x with halo: xp[b][lp][e], lp in [0,L+4), e in [0,304)
__global__ void prep_x(const float* __restrict__ q, const float* __restrict__ a,
                       unsigned short* __restrict__ xq, unsigned short* __restrict__ xa)
{
    int row = blockIdx.x;
    const float* src;
    unsigned short* dst;
    bool valid;
    if (row < NB * (LQ_ + 4)) {
        int b = row / (LQ_ + 4), lp = row - b * (LQ_ + 4);
        dst = xq + (size_t)row * EP;
        valid = (lp >= 2 && lp < 2 + LQ_);
        src = q + ((size_t)b * LQ_ + (lp - 2)) * E0;
    } else {
        int r2 = row - NB * (LQ_ + 4);
        int b = r2 / (LA_ + 4), lp = r2 - b * (LA_ + 4);
        dst = xa + (size_t)r2 * EP;
        valid = (lp >= 2 && lp < 2 + LA_);
        src = a + ((size_t)b * LA_ + (lp - 2)) * E0;
    }
    for (int e = threadIdx.x; e < EP; e += blockDim.x) {
        float v = (valid && e < E0) ? src[e] : 0.f;
        dst[e] = f2bf(v);
    }
}

// Wt[f][k'] = W[j*300+e][f] for k'=j*304+e (e<300), else 0. k'>=1520 -> 0.
__global__ void prep_w(const float* __restrict__ W, unsigned short* __restrict__ wt)
{
    int idx = blockIdx.x * 256 + threadIdx.x;      // grid sized exactly F_*KP
    int f = idx / KP;
    int k = idx - f * KP;
    int j = k / EP;
    int e = k - j * EP;
    float v = (k < 5 * EP && e < E0) ? W[(size_t)(j * E0 + e) * F_ + f] : 0.f;
    wt[idx] = f2bf(v);
}

// 128x128 tile GEMM: D[f][l] per block. A-operand = Wt rows (f), B-operand = z rows (l).
__global__ __launch_bounds__(256) void qa_gemm(
    const unsigned short* __restrict__ xq,
    const unsigned short* __restrict__ xa,
    const unsigned short* __restrict__ wt,
    const float* __restrict__ bias,
    float* __restrict__ out)
{
    __shared__ __align__(16) unsigned short lds_a[2][128 * 32]; // z tiles (rows = l)
    __shared__ __align__(16) unsigned short lds_w[2][128 * 32]; // Wt tiles (rows = f)

    const int bid = blockIdx.x;
    const int wg  = (bid & 7) * 320 + (bid >> 3);   // XCD swizzle (2560 % 8 == 0)

    const unsigned short* xp;
    float* ob;
    int Mbase, lsh, Lp, ftBase;
    if (wg < 512) {                 // question: 128 row-tiles x 4 f-tiles
        Mbase  = (wg >> 2) * 128;
        ftBase = (wg & 3) * 128;
        xp = xq; lsh = 6; Lp = LQ_ + 4;
        ob = out;
    } else {                        // answer: 512 row-tiles x 4 f-tiles
        const int id = wg - 512;
        Mbase  = (id >> 2) * 128;
        ftBase = (id & 3) * 128;
        xp = xa; lsh = 8; Lp = LA_ + 4;
        ob = out + OUTQ_ELEMS;
    }
    const int Lv = 1 << lsh;

    const int tid  = threadIdx.x;
    const int lane = tid & 63;
    const int wid  = tid >> 6;
    const int wf   = wid >> 1;      // f-quadrant
    const int wl   = wid & 1;       // l-quadrant
    const int lq   = lane >> 4;
    const int lr   = lane & 15;

    // ---- staging geometry: each wave stages 32 rows of each tile (2 x 16-row instrs)
    const int s_r = lane >> 2;                       // row within 16-row group
    const int s_g = (lane & 3) ^ ((s_r >> 1) & 3);   // pre-swizzled source chunk

    const int ar0 = Mbase + wid * 32 + s_r;
    const int ar1 = ar0 + 16;
    const int b0 = ar0 >> lsh, l0 = ar0 & (Lv - 1);
    const int b1 = ar1 >> lsh, l1 = ar1 & (Lv - 1);
    const unsigned short* gA0 = xp + (size_t)(b0 * Lp + l0) * EP + s_g * 8;
    const unsigned short* gA1 = xp + (size_t)(b1 * Lp + l1) * EP + s_g * 8;
    const unsigned short* gW0 = wt + (size_t)(ftBase + wid * 32 + s_r) * KP + s_g * 8;
    const unsigned short* gW1 = gW0 + (size_t)16 * KP;

#define STAGE(buf, kb) do {                                                              \
    __builtin_amdgcn_global_load_lds(                                                    \
        (const __attribute__((address_space(1))) void*)(gA0 + (kb)),                     \
        (__attribute__((address_space(3))) void*)(&lds_a[buf][(wid * 32) * 32]), 16, 0, 0);\
    __builtin_amdgcn_global_load_lds(                                                    \
        (const __attribute__((address_space(1))) void*)(gA1 + (kb)),                     \
        (__attribute__((address_space(3))) void*)(&lds_a[buf][(wid * 32 + 16) * 32]), 16, 0, 0);\
    __builtin_amdgcn_global_load_lds(                                                    \
        (const __attribute__((address_space(1))) void*)(gW0 + (kb)),                     \
        (__attribute__((address_space(3))) void*)(&lds_w[buf][(wid * 32) * 32]), 16, 0, 0);\
    __builtin_amdgcn_global_load_lds(                                                    \
        (const __attribute__((address_space(1))) void*)(gW1 + (kb)),                     \
        (__attribute__((address_space(3))) void*)(&lds_w[buf][(wid * 32 + 16) * 32]), 16, 0, 0);\
} while (0)

    // ---- fragment read offsets (byte), chunk-swizzled: 2-way bank spread (free)
    const int cs = (lq ^ ((lr >> 1) & 3)) * 16;
    int woff[4], aoff[4];
#pragma unroll
    for (int ms = 0; ms < 4; ++ms) woff[ms] = (wf * 64 + ms * 16 + lr) * 64 + cs;
#pragma unroll
    for (int ns = 0; ns < 4; ++ns) aoff[ns] = (wl * 64 + ns * 16 + lr) * 64 + cs;

    STAGE(0, 0);
    __syncthreads();

    f32x4 acc[4][4] = {};
    int cur = 0;
    for (int kt = 0; kt < NKT; ++kt) {
        if (kt + 1 < NKT) {
            const int kb = (kt + 1) * 32;
            STAGE(cur ^ 1, kb);
        }
        const char* la = (const char*)&lds_a[cur][0];
        const char* lw = (const char*)&lds_w[cur][0];
        short8 af[4], bfr[4];
#pragma unroll
        for (int ms = 0; ms < 4; ++ms) af[ms] = *(const short8*)(lw + woff[ms]);
#pragma unroll
        for (int ns = 0; ns < 4; ++ns) bfr[ns] = *(const short8*)(la + aoff[ns]);
#pragma unroll
        for (int ms = 0; ms < 4; ++ms)
#pragma unroll
            for (int ns = 0; ns < 4; ++ns)
                acc[ms][ns] = __builtin_amdgcn_mfma_f32_16x16x32_bf16(
                    af[ms], bfr[ns], acc[ms][ns], 0, 0, 0);
        __syncthreads();
        cur ^= 1;
    }
#undef STAGE

    // ---- epilogue: D row = f = (lane>>4)*4+reg, D col = l = lane&15 (m89-verified)
#pragma unroll
    for (int ns = 0; ns < 4; ++ns) {
        const int m = Mbase + wl * 64 + ns * 16 + lr;
        const int b = m >> lsh;
        const int l = m & (Lv - 1);
        float* orow = ob + ((size_t)b * F_ << lsh) + l;
#pragma unroll
        for (int ms = 0; ms < 4; ++ms) {
            const int f0 = ftBase + wf * 64 + ms * 16 + lq * 4;
            const f32x4 v = acc[ms][ns];
#pragma unroll
            for (int r = 0; r < 4; ++r) {
                const int f = f0 + r;
                orow[(size_t)f << lsh] = v[r] + __ldg(&bias[f]);
            }
        }
    }
}

extern "C" void kernel_launch(void* const* d_in, const int* in_sizes, int n_in,
                              void* d_out, int out_size, void* d_ws, size_t ws_size,
                              hipStream_t stream)
{
    const float* q    = (const float*)d_in[0];
    const float* a    = (const float*)d_in[1];
    const float* W    = (const float*)d_in[2];
    const float* bias = (const float*)d_in[3];
    float* out = (float*)d_out;

    unsigned short* xq = (unsigned short*)d_ws;
    unsigned short* xa = xq + XQ_ELEMS;
    unsigned short* wt = xa + XA_ELEMS;
    // ws needed: (XQ+XA+WT)*2 = 52.6 MB

    const int xrows = NB * (LQ_ + 4) + NB * (LA_ + 4);   // 83,968
    prep_x<<<xrows, 128, 0, stream>>>(q, a, xq, xa);
    prep_w<<<(F_ * KP) / 256, 256, 0, stream>>>(W, wt);
    qa_gemm<<<2560, 256, 0, stream>>>(xq, xa, wt, bias, out);
}

// Round 2
// 229.663 us; speedup vs baseline: 1.2061x; 1.2061x over previous
//
#include <hip/hip_runtime.h>

// Shapes
#define NB   256      // batch
#define E0   300      // embedding
#define EP   304      // padded embedding
#define F_   512      // features
#define KP   1536     // padded K (5*304=1520 -> 48*32)
#define NKT  48       // K-steps of 32
#define LQ_  64
#define LA_  256

typedef __attribute__((ext_vector_type(4))) float f32x4;
typedef __attribute__((ext_vector_type(8))) short short8;

#define XQ_ELEMS (NB * (LQ_ + 4) * EP)   // 5,292,032
#define XA_ELEMS (NB * (LA_ + 4) * EP)   // 20,234,240
#define OUTQ_ELEMS ((size_t)NB * F_ * LQ_)

__device__ __forceinline__ unsigned short f2bf(float x) {
    unsigned int u = __float_as_uint(x);
    u = u + 0x7fffu + ((u >> 16) & 1u);   // RNE
    return (unsigned short)(u >> 16);
}

// Build zero-padded bf16 x with halo: xp[b][lp][e], lp in [0,L+4), e in [0,304)
__global__ void prep_x(const float* __restrict__ q, const float* __restrict__ a,
                       unsigned short* __restrict__ xq, unsigned short* __restrict__ xa)
{
    int row = blockIdx.x;
    const float* src;
    unsigned short* dst;
    bool valid;
    if (row < NB * (LQ_ + 4)) {
        int b = row / (LQ_ + 4), lp = row - b * (LQ_ + 4);
        dst = xq + (size_t)row * EP;
        valid = (lp >= 2 && lp < 2 + LQ_);
        src = q + ((size_t)b * LQ_ + (lp - 2)) * E0;
    } else {
        int r2 = row - NB * (LQ_ + 4);
        int b = r2 / (LA_ + 4), lp = r2 - b * (LA_ + 4);
        dst = xa + (size_t)r2 * EP;
        valid = (lp >= 2 && lp < 2 + LA_);
        src = a + ((size_t)b * LA_ + (lp - 2)) * E0;
    }
    for (int e = threadIdx.x; e < EP; e += blockDim.x) {
        float v = (valid && e < E0) ? src[e] : 0.f;
        dst[e] = f2bf(v);
    }
}

// Wt[f][k'] = W[j*300+e][f] for k'=j*304+e (e<300), else 0.
__global__ void prep_w(const float* __restrict__ W, unsigned short* __restrict__ wt)
{
    int idx = blockIdx.x * 256 + threadIdx.x;
    int f = idx / KP;
    int k = idx - f * KP;
    int j = k / EP;
    int e = k - j * EP;
    float v = (k < 5 * EP && e < E0) ? W[(size_t)(j * E0 + e) * F_ + f] : 0.f;
    wt[idx] = f2bf(v);
}

// 256x256 tile, 8 waves (2f x 4l), per-wave 128x64, BK=32, ring-4 LDS,
// counted-vmcnt pipeline (never drains to 0 in the main loop).
__global__ __launch_bounds__(512, 2) void qa_gemm(
    const unsigned short* __restrict__ xq,
    const unsigned short* __restrict__ xa,
    const unsigned short* __restrict__ wt,
    const float* __restrict__ bias,
    float* __restrict__ out)
{
    // ring buffer: [4][ W 256x32 | Z 256x32 ] bf16 = 4 x 32 KB = 128 KB
    __shared__ __align__(16) unsigned short lds[4 * 16384];

    const int bid = blockIdx.x;
    const int wg  = (bid & 7) * 80 + (bid >> 3);   // XCD swizzle, 640 % 8 == 0

    const unsigned short* xp;
    float* ob;
    int Mbase, lsh, Lp, ftBase;
    if (wg < 128) {                 // question: 64 M-tiles x 2 f-tiles
        Mbase  = (wg >> 1) * 256;
        ftBase = (wg & 1) * 256;
        xp = xq; lsh = 6; Lp = LQ_ + 4;
        ob = out;
    } else {                        // answer: 256 M-tiles x 2 f-tiles
        const int id = wg - 128;
        Mbase  = (id >> 1) * 256;
        ftBase = (id & 1) * 256;
        xp = xa; lsh = 8; Lp = LA_ + 4;
        ob = out + OUTQ_ELEMS;
    }
    const int Lv = 1 << lsh;

    const int tid  = threadIdx.x;
    const int lane = tid & 63;
    const int wid  = tid >> 6;
    const int wf   = wid >> 2;      // f half   (0..1) -> 128 f rows
    const int wn   = wid & 3;       // l quarter(0..3) -> 64 l rows
    const int lq   = lane >> 4;
    const int lr   = lane & 15;

    // ---- staging geometry: per K-tile, 16 instrs/operand; wave wid instr j
    //      covers rows (wid*2+j)*16..+16 (16 rows x 4 chunks of 16B, linear LDS)
    const int s_c  = (lane & 3) ^ ((lane >> 3) & 3);   // inverse-swizzled src chunk
    const int sub  = lane >> 2;                         // row within 16-row group
    const int srow0 = (wid * 2 + 0) * 16 + sub;
    const int srow1 = (wid * 2 + 1) * 16 + sub;

    const unsigned short* gW0 = wt + (size_t)(ftBase + srow0) * KP + s_c * 8;
    const unsigned short* gW1 = wt + (size_t)(ftBase + srow1) * KP + s_c * 8;
    const int mr0 = Mbase + srow0, mr1 = Mbase + srow1;
    const unsigned short* gZ0 = xp + (size_t)((mr0 >> lsh) * Lp + (mr0 & (Lv - 1))) * EP + s_c * 8;
    const unsigned short* gZ1 = xp + (size_t)((mr1 >> lsh) * Lp + (mr1 & (Lv - 1))) * EP + s_c * 8;

    unsigned short* dW0 = &lds[0] + (wid * 2 + 0) * 512;
    unsigned short* dW1 = &lds[0] + (wid * 2 + 1) * 512;
    unsigned short* dZ0 = dW0 + 8192;
    unsigned short* dZ1 = dW1 + 8192;

#define STAGE(T) do { const int rb = ((T) & 3) * 16384; const size_t ko = (size_t)(T) * 32; \
    __builtin_amdgcn_global_load_lds((const __attribute__((address_space(1))) void*)(gW0 + ko), \
        (__attribute__((address_space(3))) void*)(dW0 + rb), 16, 0, 0);                          \
    __builtin_amdgcn_global_load_lds((const __attribute__((address_space(1))) void*)(gW1 + ko), \
        (__attribute__((address_space(3))) void*)(dW1 + rb), 16, 0, 0);                          \
    __builtin_amdgcn_global_load_lds((const __attribute__((address_space(1))) void*)(gZ0 + ko), \
        (__attribute__((address_space(3))) void*)(dZ0 + rb), 16, 0, 0);                          \
    __builtin_amdgcn_global_load_lds((const __attribute__((address_space(1))) void*)(gZ1 + ko), \
        (__attribute__((address_space(3))) void*)(dZ1 + rb), 16, 0, 0);                          \
} while (0)

    // ---- fragment read offsets (bytes), chunk-swizzled (same scheme as verified r1)
    const int cs = (lq ^ ((lr >> 1) & 3)) * 16;
    int woff[8], zoff[4];
#pragma unroll
    for (int m = 0; m < 8; ++m) woff[m] = (wf * 128 + m * 16 + lr) * 64 + cs;
#pragma unroll
    for (int n = 0; n < 4; ++n) zoff[n] = (wn * 64 + n * 16 + lr) * 64 + cs + 16384;

    f32x4 acc[8][4] = {};

#define STEP_COMPUTE(T) do { const char* bb = (const char*)&lds[((T) & 3) * 16384]; \
    short8 afr[8]; short8 bfr[4];                                                    \
    _Pragma("unroll") for (int m = 0; m < 8; ++m) afr[m] = *(const short8*)(bb + woff[m]); \
    _Pragma("unroll") for (int n = 0; n < 4; ++n) bfr[n] = *(const short8*)(bb + zoff[n]); \
    __builtin_amdgcn_s_setprio(1);                                                   \
    _Pragma("unroll") for (int m = 0; m < 8; ++m)                                    \
    _Pragma("unroll") for (int n = 0; n < 4; ++n)                                    \
        acc[m][n] = __builtin_amdgcn_mfma_f32_16x16x32_bf16(afr[m], bfr[n], acc[m][n], 0, 0, 0); \
    __builtin_amdgcn_s_setprio(0);                                                   \
} while (0)

#define WAITBAR8 asm volatile("s_waitcnt vmcnt(8)\n\ts_barrier" ::: "memory")
#define WAITBAR4 asm volatile("s_waitcnt vmcnt(4)\n\ts_barrier" ::: "memory")
#define WAITBAR0 asm volatile("s_waitcnt vmcnt(0)\n\ts_barrier" ::: "memory")

    // prologue: stage tiles 0,1,2 (12 instrs); confirm tile 0 (leave 8 in flight)
    STAGE(0); STAGE(1); STAGE(2);
    WAITBAR8;

    // steady state: stage t+3 (into buf freed at end of step t-1), compute t,
    // then confirm tile t+1 (stages of t+2,t+3 = 8 instrs stay in flight).
    for (int t = 0; t < 45; ++t) {
        STAGE(t + 3);
        STEP_COMPUTE(t);
        WAITBAR8;
    }
    STEP_COMPUTE(45); WAITBAR4;   // confirm 46
    STEP_COMPUTE(46); WAITBAR0;   // confirm 47
    STEP_COMPUTE(47);

#undef STAGE
#undef STEP_COMPUTE

    // ---- epilogue: D row = f = lq*4+reg, col = l = lr (verified r1)
#pragma unroll
    for (int ns = 0; ns < 4; ++ns) {
        const int m = Mbase + wn * 64 + ns * 16 + lr;
        const int b = m >> lsh;
        const int l = m & (Lv - 1);
        float* orow = ob + ((size_t)b * F_ << lsh) + l;
#pragma unroll
        for (int ms = 0; ms < 8; ++ms) {
            const int f0 = ftBase + wf * 128 + ms * 16 + lq * 4;
            const f32x4 v = acc[ms][ns];
#pragma unroll
            for (int r = 0; r < 4; ++r) {
                const int f = f0 + r;
                orow[(size_t)f << lsh] = v[r] + __ldg(&bias[f]);
            }
        }
    }
}

extern "C" void kernel_launch(void* const* d_in, const int* in_sizes, int n_in,
                              void* d_out, int out_size, void* d_ws, size_t ws_size,
                              hipStream_t stream)
{
    const float* q    = (const float*)d_in[0];
    const float* a    = (const float*)d_in[1];
    const float* W    = (const float*)d_in[2];
    const float* bias = (const float*)d_in[3];
    float* out = (float*)d_out;

    unsigned short* xq = (unsigned short*)d_ws;
    unsigned short* xa = xq + XQ_ELEMS;
    unsigned short* wt = xa + XA_ELEMS;
    // ws needed: (XQ+XA+WT)*2 = 52.6 MB

    const int xrows = NB * (LQ_ + 4) + NB * (LA_ + 4);   // 83,968
    prep_x<<<xrows, 128, 0, stream>>>(q, a, xq, xa);
    prep_w<<<(F_ * KP) / 256, 256, 0, stream>>>(W, wt);
    qa_gemm<<<640, 512, 0, stream>>>(xq, xa, wt, bias, out);
}